// Round 7
// baseline (2017.403 us; speedup 1.0000x reference)
//
#include <hip/hip_runtime.h>

#define EPS 1e-05f
#define ALPHA 0.05f

typedef _Float16 h2v __attribute__((ext_vector_type(2)));
typedef _Float16 f16x8 __attribute__((ext_vector_type(8)));
typedef float f32x16 __attribute__((ext_vector_type(16)));

__device__ __forceinline__ float rcp_f(float x){ return __builtin_amdgcn_rcpf(x); }
__device__ __forceinline__ float dot2(h2v a, h2v b, float c){
  return __builtin_amdgcn_fdot2(a, b, c, false);
}
__device__ __forceinline__ h2v uh(uint u){ return __builtin_bit_cast(h2v, u); }
__device__ __forceinline__ float uf(uint u){ return __builtin_bit_cast(float, u); }

#define LOG2E 1.4426950408889634f
#define LN2   0.6931471805599453f

__device__ __forceinline__ float fast_tanh(float x){
  float ax = fabsf(x);
  float e  = exp2f(ax * (-2.0f * LOG2E));
  float t  = (1.0f - e) * rcp_f(1.0f + e);
  return copysignf(t, x);
}
__device__ __forceinline__ float fast_sp(float x){
  float ax = fabsf(x);
  float e  = exp2f(ax * -LOG2E);
  return fmaxf(x, 0.0f) + log2f(1.0f + e) * LN2;
}
__device__ __forceinline__ float fast_sig(float x){
  float ax = fabsf(x);
  float e  = exp2f(ax * -LOG2E);
  float r  = rcp_f(1.0f + e);
  return x >= 0.0f ? r : e * r;
}
__device__ __forceinline__ float sig_from_sp(float sp){
  return 1.0f - exp2f(sp * -LOG2E);
}
__device__ __forceinline__ h2v mkh2(float a, float b){
  h2v r; r.x = (_Float16)a; r.y = (_Float16)b; return r;
}
__device__ __forceinline__ uint packh(float a, float b){
  ushort lo = __builtin_bit_cast(ushort, (_Float16)a);
  ushort hi = __builtin_bit_cast(ushort, (_Float16)b);
  return (uint)lo | ((uint)hi << 16);
}
__device__ __forceinline__ float f16lo(uint u){
  return (float)__builtin_bit_cast(_Float16, (ushort)(u & 0xffffu));
}
__device__ __forceinline__ float f16hi(uint u){
  return (float)__builtin_bit_cast(_Float16, (ushort)(u >> 16));
}

// ================= fused kernel: stage + pack + yref + compute =================
__global__ __launch_bounds__(512, 2) void holo_main(
    const float* __restrict__ X, const float* __restrict__ U,
    const float* __restrict__ xref,
    const float* __restrict__ fw1, const float* __restrict__ fb1,
    const float* __restrict__ fw2, const float* __restrict__ fb2,
    const float* __restrict__ fw3, const float* __restrict__ fb3,
    const float* __restrict__ gw,  const float* __restrict__ gb,
    const float* __restrict__ iw1, const float* __restrict__ ib1,
    const float* __restrict__ iw2, const float* __restrict__ ib2,
    const float* __restrict__ iw3, const float* __restrict__ ib3,
    const float* __restrict__ iw4, const float* __restrict__ ib4,
    const float* __restrict__ im2, const float* __restrict__ im3,
    const float* __restrict__ im4,
    float* __restrict__ out, int N)
{
  // ---- LDS (natural layouts, zero-padded; reads use runtime hh offsets) ----
  __shared__ alignas(16) ushort sW2r[224*84]; // fw2 MFMA-A [224 rows][84 halves]
  __shared__ uint4 sW3E[224];   // 112 n-pairs x2: {w3 d0..d5 pairs, fb2[n], fb2[n+1]}
  __shared__ alignas(16) ushort sA2[64*68];   // iw2 MFMA-A [64 rows j][68 halves k]
  __shared__ uint4 sPW1B[80];   // fw1 row o: {w01,w23,w45, fb1[o]}
  __shared__ uint4 sPGB[36];    // gw  row o: {w01,w23,w45, gb[o]}
  __shared__ uint4 sPI1B[60];   // iw1 rows: {w,b} pairs
  __shared__ uint4 sPI1C[60];   // iw1^T pairs [30 kp][6 d + pad]
  __shared__ uint4 sPI3[240];   // iw3 [30 i3][32 jp] (jp 30,31 = 0)
  __shared__ uint4 sPI3C[256];  // iw3^T [64 j][16 qp] (rows 60-63, qp 15 = 0)
  __shared__ uint4 sPM2B[64];   // im2 row j: {w01,w23,w45, ib2[j]} (rows 60-63 = 0)
  __shared__ uint4 sPM2C[64];   // im2^T [32 jp][8] (jp 30,31 = 0)
  __shared__ uint4 sPM3B[60];   // im3 rows: {w,ib3 | iw4,0,0,0}
  __shared__ uint4 sPM3C[30];   // im3^T [15 qp][8]
  __shared__ uint  sPM4u[4];    // im4 pairs
  __shared__ alignas(16) uint sPI2Cu[60*32]; // iw2^T [60 k1][32 jp] (jp 30,31 = 0)
  __shared__ float sFB3[6], sXREF[6], sIM4[6];
  __shared__ float sS1[60], sS2[60], sS3[30];
  __shared__ float sYREF, sIB4;

  const int t = threadIdx.x;
  const int T = 512;
  const int lane = t & 63;
  const int hh  = lane >> 5;
  const int l31 = lane & 31;

  // ---- stage + pack from original weights ----
  for (int idx=t; idx<224*42; idx+=T){
    int row = idx/42, c = idx%42, k = 2*c;
    uint v = 0;
    if (row < 200 && k < 80) v = packh(fw2[row*80+k], fw2[row*80+k+1]);
    ((uint*)sW2r)[idx] = v;
  }
  for (int idx=t; idx<896; idx+=T){
    int P = idx/8, c = idx%8, n = 2*P;
    uint v = 0;
    if (n < 200){
      if (c < 6)       v = packh(fw3[c*200+n], fw3[c*200+n+1]);
      else if (c == 6) v = __builtin_bit_cast(uint, fb2[n]);
      else             v = __builtin_bit_cast(uint, fb2[n+1]);
    }
    ((uint*)sW3E)[idx] = v;
  }
  for (int idx=t; idx<64*34; idx+=T){           // sA2
    int row = idx/34, c = idx%34, k = 2*c;
    uint v = 0;
    if (row < 60 && c < 30) v = packh(iw2[row*60+k], iw2[row*60+k+1]);
    ((uint*)sA2)[idx] = v;
  }
  for (int idx=t; idx<320; idx+=T){
    int o = idx/4, c = idx%4;
    ((uint*)sPW1B)[idx] = (c<3) ? packh(fw1[o*6+2*c], fw1[o*6+2*c+1])
                                : __builtin_bit_cast(uint, fb1[o]);
  }
  for (int idx=t; idx<144; idx+=T){
    int o = idx/4, c = idx%4;
    ((uint*)sPGB)[idx] = (c<3) ? packh(gw[o*6+2*c], gw[o*6+2*c+1])
                               : __builtin_bit_cast(uint, gb[o]);
  }
  for (int idx=t; idx<240; idx+=T){
    int p = idx/8, c = idx%8, sub = c/4, cc = c%4, nr = 2*p+sub;
    ((uint*)sPI1B)[idx] = (cc<3) ? packh(iw1[nr*6+2*cc], iw1[nr*6+2*cc+1])
                                 : __builtin_bit_cast(uint, ib1[nr]);
  }
  for (int idx=t; idx<240; idx+=T){
    int q = idx/8, c = idx%8;
    ((uint*)sPI1C)[idx] = (c<6) ? packh(iw1[(2*q)*6+c], iw1[(2*q+1)*6+c]) : 0u;
  }
  for (int idx=t; idx<960; idx+=T){
    int r = idx/32, q = idx%32;
    ((uint*)sPI3)[idx] = (q<30) ? packh(iw3[r*60+2*q], iw3[r*60+2*q+1]) : 0u;
  }
  for (int idx=t; idx<1024; idx+=T){
    int j = idx/16, q = idx%16;
    ((uint*)sPI3C)[idx] = (j<60 && q<15) ? packh(iw3[(2*q)*60+j], iw3[(2*q+1)*60+j]) : 0u;
  }
  for (int idx=t; idx<256; idx+=T){
    int j = idx/4, c = idx%4;
    uint v = 0;
    if (j < 60) v = (c<3) ? packh(im2[j*6+2*c], im2[j*6+2*c+1])
                          : __builtin_bit_cast(uint, ib2[j]);
    ((uint*)sPM2B)[idx] = v;
  }
  for (int idx=t; idx<256; idx+=T){
    int q = idx/8, c = idx%8;
    ((uint*)sPM2C)[idx] = (q<30 && c<6) ? packh(im2[(2*q)*6+c], im2[(2*q+1)*6+c]) : 0u;
  }
  for (int idx=t; idx<240; idx+=T){
    int r = idx/8, c = idx%8;
    uint v = 0;
    if (c < 3)       v = packh(im3[r*6+2*c], im3[r*6+2*c+1]);
    else if (c == 3) v = __builtin_bit_cast(uint, ib3[r]);
    else if (c == 4) v = __builtin_bit_cast(uint, iw4[r]);
    ((uint*)sPM3B)[idx] = v;
  }
  for (int idx=t; idx<120; idx+=T){
    int q = idx/8, c = idx%8;
    ((uint*)sPM3C)[idx] = (c<6) ? packh(im3[(2*q)*6+c], im3[(2*q+1)*6+c]) : 0u;
  }
  for (int idx=t; idx<4; idx+=T)
    sPM4u[idx] = (idx<3) ? packh(im4[2*idx], im4[2*idx+1]) : 0u;
  for (int idx=t; idx<1920; idx+=T){
    int k1 = idx/32, q = idx%32;
    sPI2Cu[idx] = (q<30) ? packh(iw2[(2*q)*60+k1], iw2[(2*q+1)*60+k1]) : 0u;
  }
  for (int k=t;k<6;k+=T){ sFB3[k]=fb3[k]; sIM4[k]=im4[k]; sXREF[k]=xref[k]; }
  if (t==0) sIB4=ib4[0];
  __syncthreads();

  // ---- cooperative yref = icnn(xref) from the SAME packed f16 weights ----
  {
    h2v xrp[3];
    #pragma unroll
    for (int p = 0; p < 3; p++) xrp[p] = mkh2(sXREF[2*p], sXREF[2*p+1]);
    if (t < 60){
      const uint* w = (const uint*)sPI1B + (t/2)*8 + (t&1)*4;
      float z = uf(w[3]);
      #pragma unroll
      for (int c = 0; c < 3; c++) z = dot2(uh(w[c]), xrp[c], z);
      sS1[t] = fast_sp(z);
    }
    __syncthreads();
    if (t < 60){
      const uint* m = (const uint*)sPM2B + t*4;
      float z = uf(m[3]);
      #pragma unroll
      for (int c = 0; c < 3; c++) z = dot2(uh(m[c]), xrp[c], z);
      const uint* arow = (const uint*)sA2 + t*34;
      for (int q = 0; q < 30; q++)
        z = dot2(uh(arow[q]), mkh2(sS1[2*q], sS1[2*q+1]), z);
      sS2[t] = fast_sp(z);
    }
    __syncthreads();
    if (t < 30){
      const uint* m = (const uint*)sPM3B + t*8;
      float z = uf(m[3]);
      #pragma unroll
      for (int c = 0; c < 3; c++) z = dot2(uh(m[c]), xrp[c], z);
      const uint* prow = (const uint*)sPI3 + t*32;
      for (int q = 0; q < 30; q++)
        z = dot2(uh(prow[q]), mkh2(sS2[2*q], sS2[2*q+1]), z);
      sS3[t] = fast_sp(z);
    }
    __syncthreads();
    if (t == 0){
      float y = sIB4;
      #pragma unroll
      for (int p = 0; p < 3; p++) y = dot2(uh(sPM4u[p]), xrp[p], y);
      for (int j = 0; j < 30; j++) y = fmaf(uf(((const uint*)sPM3B)[j*8+4]), sS3[j], y);
      sYREF = y;
    }
    __syncthreads();
  }

  // ---- per-thread sample compute (guarded loads/stores, full-wave execution) ----
  const int i = blockIdx.x * blockDim.x + t;
  const bool valid = (i < N);

  float x[6]; h2v xp[3];
  #pragma unroll
  for (int k = 0; k < 6; k++) x[k] = valid ? X[(long)i*6 + k] : 0.0f;
  #pragma unroll
  for (int p = 0; p < 3; p++) xp[p] = mkh2(x[2*p], x[2*p+1]);

  // ============ FNN layer 1: 6 -> 80, tanh ============
  uint h1u[40];
  #pragma unroll
  for (int o = 0; o < 80; o += 2){
    uint4 wa = sPW1B[o], wb = sPW1B[o+1];
    float z0 = uf(wa.w), z1 = uf(wb.w);
    z0 = dot2(uh(wa.x), xp[0], z0); z0 = dot2(uh(wa.y), xp[1], z0); z0 = dot2(uh(wa.z), xp[2], z0);
    z1 = dot2(uh(wb.x), xp[0], z1); z1 = dot2(uh(wb.y), xp[1], z1); z1 = dot2(uh(wb.z), xp[2], z1);
    h1u[o/2] = packh(fast_tanh(z0), fast_tanh(z1));
  }

  // ============ FNN L2+L3 via MFMA (32x32x16 f16) ============
  uint bf0[5][4], bf1[5][4];
  {
    int a0 = 4 * l31;
    int a1 = 4 * (32 + l31);
    #pragma unroll
    for (int kt = 0; kt < 5; kt++){
      #pragma unroll
      for (int q = 0; q < 4; q++){
        int lo0 = __builtin_amdgcn_ds_bpermute(a0, (int)h1u[kt*8 + q]);
        int hi0 = __builtin_amdgcn_ds_bpermute(a0, (int)h1u[kt*8 + 4 + q]);
        bf0[kt][q] = hh ? (uint)hi0 : (uint)lo0;
        int lo1 = __builtin_amdgcn_ds_bpermute(a1, (int)h1u[kt*8 + q]);
        int hi1 = __builtin_amdgcn_ds_bpermute(a1, (int)h1u[kt*8 + 4 + q]);
        bf1[kt][q] = hh ? (uint)hi1 : (uint)lo1;
      }
    }
  }

  float fp0[6] = {0.f,0.f,0.f,0.f,0.f,0.f};
  float fp1[6] = {0.f,0.f,0.f,0.f,0.f,0.f};
  for (int mt = 0; mt < 7; mt++){
    const int row = mt*32 + l31;
    f16x8 af[5];
    #pragma unroll
    for (int kt = 0; kt < 5; kt++){
      const ushort* wp = &sW2r[row*84 + kt*16 + 8*hh];
      uint2 w0 = *(const uint2*)wp;
      uint2 w1 = *(const uint2*)(wp + 4);
      uint4 au; au.x = w0.x; au.y = w0.y; au.z = w1.x; au.w = w1.y;
      af[kt] = __builtin_bit_cast(f16x8, au);
    }
    f32x16 acc0 = {0,0,0,0,0,0,0,0,0,0,0,0,0,0,0,0};
    f32x16 acc1 = {0,0,0,0,0,0,0,0,0,0,0,0,0,0,0,0};
    #pragma unroll
    for (int kt = 0; kt < 5; kt++){
      uint4 b0u; b0u.x=bf0[kt][0]; b0u.y=bf0[kt][1]; b0u.z=bf0[kt][2]; b0u.w=bf0[kt][3];
      uint4 b1u; b1u.x=bf1[kt][0]; b1u.y=bf1[kt][1]; b1u.z=bf1[kt][2]; b1u.w=bf1[kt][3];
      acc0 = __builtin_amdgcn_mfma_f32_32x32x16_f16(af[kt], __builtin_bit_cast(f16x8, b0u), acc0, 0, 0, 0);
      acc1 = __builtin_amdgcn_mfma_f32_32x32x16_f16(af[kt], __builtin_bit_cast(f16x8, b1u), acc1, 0, 0, 0);
    }
    // epilogue (neuron pairs); rows 200-223 are zero-pad -> mt==6 keeps only c==0
    #pragma unroll
    for (int c = 0; c < 4; c++){
      #pragma unroll
      for (int b0h = 0; b0h < 2; b0h++){
        if (mt == 6 && c > 0) continue;
        const int r0 = 4*c + 2*b0h;
        const int P  = mt*16 + 4*c + 2*hh + b0h;
        uint4 wa = sW3E[P*2], wb = sW3E[P*2+1];
        float bA = uf(wb.z), bB = uf(wb.w);
        h2v tp0 = mkh2(fast_tanh(acc0[r0] + bA), fast_tanh(acc0[r0+1] + bB));
        h2v tp1 = mkh2(fast_tanh(acc1[r0] + bA), fast_tanh(acc1[r0+1] + bB));
        fp0[0] = dot2(uh(wa.x), tp0, fp0[0]); fp1[0] = dot2(uh(wa.x), tp1, fp1[0]);
        fp0[1] = dot2(uh(wa.y), tp0, fp0[1]); fp1[1] = dot2(uh(wa.y), tp1, fp1[1]);
        fp0[2] = dot2(uh(wa.z), tp0, fp0[2]); fp1[2] = dot2(uh(wa.z), tp1, fp1[2]);
        fp0[3] = dot2(uh(wa.w), tp0, fp0[3]); fp1[3] = dot2(uh(wa.w), tp1, fp1[3]);
        fp0[4] = dot2(uh(wb.x), tp0, fp0[4]); fp1[4] = dot2(uh(wb.x), tp1, fp1[4]);
        fp0[5] = dot2(uh(wb.y), tp0, fp0[5]); fp1[5] = dot2(uh(wb.y), tp1, fp1[5]);
      }
    }
  }
  float f[6];
  #pragma unroll
  for (int d = 0; d < 6; d++){
    float s0 = fp0[d] + __shfl_xor(fp0[d], 32, 64);
    float s1 = fp1[d] + __shfl_xor(fp1[d], 32, 64);
    f[d] = sFB3[d] + (hh ? s1 : s0);
  }

  // ============ ICNN z1 -> sp1 packed ============
  uint sp1p[32];
  #pragma unroll
  for (int p = 0; p < 30; p++){
    uint4 wA = sPI1B[2*p], wB = sPI1B[2*p+1];
    float za = uf(wA.w), zb = uf(wB.w);
    za = dot2(uh(wA.x), xp[0], za); za = dot2(uh(wA.y), xp[1], za); za = dot2(uh(wA.z), xp[2], za);
    zb = dot2(uh(wB.x), xp[0], zb); zb = dot2(uh(wB.y), xp[1], zb); zb = dot2(uh(wB.z), xp[2], zb);
    sp1p[p] = packh(fast_sp(za), fast_sp(zb));
  }
  sp1p[30] = 0u; sp1p[31] = 0u;

  // ============ z2 = W2*sp1 via MFMA ============
  uint zbf0[4][4], zbf1[4][4];
  {
    int a0 = 4 * l31;
    int a1 = 4 * (32 + l31);
    #pragma unroll
    for (int kt = 0; kt < 4; kt++){
      #pragma unroll
      for (int q = 0; q < 4; q++){
        int lo0 = __builtin_amdgcn_ds_bpermute(a0, (int)sp1p[kt*8 + q]);
        int hi0 = __builtin_amdgcn_ds_bpermute(a0, (int)sp1p[kt*8 + 4 + q]);
        zbf0[kt][q] = hh ? (uint)hi0 : (uint)lo0;
        int lo1 = __builtin_amdgcn_ds_bpermute(a1, (int)sp1p[kt*8 + q]);
        int hi1 = __builtin_amdgcn_ds_bpermute(a1, (int)sp1p[kt*8 + 4 + q]);
        zbf1[kt][q] = hh ? (uint)hi1 : (uint)lo1;
      }
    }
  }
  f32x16 zacc[2][2];
  {
    f32x16 Z = {0,0,0,0,0,0,0,0,0,0,0,0,0,0,0,0};
    zacc[0][0]=Z; zacc[0][1]=Z; zacc[1][0]=Z; zacc[1][1]=Z;
  }
  #pragma unroll
  for (int m = 0; m < 2; m++){
    f16x8 af[4];
    #pragma unroll
    for (int kt = 0; kt < 4; kt++){
      const ushort* wp = &sA2[(m*32+l31)*68 + kt*16 + 8*hh];
      uint2 w0 = *(const uint2*)wp;
      uint2 w1 = *(const uint2*)(wp + 4);
      uint4 au; au.x = w0.x; au.y = w0.y; au.z = w1.x; au.w = w1.y;
      af[kt] = __builtin_bit_cast(f16x8, au);
    }
    #pragma unroll
    for (int kt = 0; kt < 4; kt++){
      uint4 b0u; b0u.x=zbf0[kt][0]; b0u.y=zbf0[kt][1]; b0u.z=zbf0[kt][2]; b0u.w=zbf0[kt][3];
      uint4 b1u; b1u.x=zbf1[kt][0]; b1u.y=zbf1[kt][1]; b1u.z=zbf1[kt][2]; b1u.w=zbf1[kt][3];
      zacc[m][0] = __builtin_amdgcn_mfma_f32_32x32x16_f16(af[kt], __builtin_bit_cast(f16x8, b0u), zacc[m][0], 0, 0, 0);
      zacc[m][1] = __builtin_amdgcn_mfma_f32_32x32x16_f16(af[kt], __builtin_bit_cast(f16x8, b1u), zacc[m][1], 0, 0, 0);
    }
  }
  // exchange the partner-half rows (send opposite-nt, f16-packed)
  uint ru[2][8];
  #pragma unroll
  for (int m = 0; m < 2; m++){
    #pragma unroll
    for (int rp = 0; rp < 8; rp++){
      float s0 = hh ? zacc[m][0][2*rp]   : zacc[m][1][2*rp];
      float s1 = hh ? zacc[m][0][2*rp+1] : zacc[m][1][2*rp+1];
      ru[m][rp] = (uint)__shfl_xor((int)packh(s0, s1), 32, 64);
    }
  }
  // assemble c2p[32] in slot order: [own 16 pairs | partner 16 pairs]
  // own slot (m,rp): rows m*32 + pb(rp) + 4*hh, +1 ; partner: +4*(1-hh)
  uint c2p[32];
  #pragma unroll
  for (int m = 0; m < 2; m++){
    #pragma unroll
    for (int rp = 0; rp < 8; rp++){
      const int pb = 2*(rp&1) + 8*(rp>>1);
      int rowb = m*32 + pb + 4*hh;
      uint4 i0 = sPM2B[rowb], i1 = sPM2B[rowb+1];
      float zlo = uf(i0.w) + (hh ? zacc[m][1][2*rp]   : zacc[m][0][2*rp]);
      float zhi = uf(i1.w) + (hh ? zacc[m][1][2*rp+1] : zacc[m][0][2*rp+1]);
      zlo = dot2(uh(i0.x), xp[0], zlo); zlo = dot2(uh(i0.y), xp[1], zlo); zlo = dot2(uh(i0.z), xp[2], zlo);
      zhi = dot2(uh(i1.x), xp[0], zhi); zhi = dot2(uh(i1.y), xp[1], zhi); zhi = dot2(uh(i1.z), xp[2], zhi);
      c2p[m*8+rp] = packh(fast_sp(zlo), fast_sp(zhi));
      int rowb2 = m*32 + pb + 4 - 4*hh;
      uint4 j0 = sPM2B[rowb2], j1 = sPM2B[rowb2+1];
      float plo = uf(j0.w) + f16lo(ru[m][rp]);
      float phi = uf(j1.w) + f16hi(ru[m][rp]);
      plo = dot2(uh(j0.x), xp[0], plo); plo = dot2(uh(j0.y), xp[1], plo); plo = dot2(uh(j0.z), xp[2], plo);
      phi = dot2(uh(j1.x), xp[0], phi); phi = dot2(uh(j1.y), xp[1], phi); phi = dot2(uh(j1.z), xp[2], phi);
      c2p[16+m*8+rp] = packh(fast_sp(plo), fast_sp(phi));
    }
  }

  // ============ z3 fwd + y + g3 (slot-addressed weight reads) ============
  float y = sIB4;
  #pragma unroll
  for (int p = 0; p < 3; p++) y = dot2(uh(sPM4u[p]), xp[p], y);
  float ac[6];
  #pragma unroll
  for (int d = 0; d < 6; d++) ac[d] = sIM4[d];
  float g3[30];
  #pragma unroll
  for (int i3 = 0; i3 < 30; i3++){
    uint4 m0 = sPM3B[2*i3], m1 = sPM3B[2*i3+1];
    float z = uf(m0.w);
    z = dot2(uh(m0.x), xp[0], z); z = dot2(uh(m0.y), xp[1], z); z = dot2(uh(m0.z), xp[2], z);
    const uint* prow = (const uint*)sPI3 + i3*32;
    #pragma unroll
    for (int m = 0; m < 2; m++){
      #pragma unroll
      for (int rg = 0; rg < 4; rg++){
        const int o = m*16 + rg*4;
        uint2 vo = *(const uint2*)(prow + o + 2*hh);
        z = dot2(uh(vo.x), uh(c2p[m*8+2*rg]),   z);
        z = dot2(uh(vo.y), uh(c2p[m*8+2*rg+1]), z);
        uint2 vp = *(const uint2*)(prow + o + 2 - 2*hh);
        z = dot2(uh(vp.x), uh(c2p[16+m*8+2*rg]),   z);
        z = dot2(uh(vp.y), uh(c2p[16+m*8+2*rg+1]), z);
      }
    }
    float sp3 = fast_sp(z);
    float w4  = uf(m1.x);
    y = fmaf(w4, sp3, y);
    g3[i3] = w4 * sig_from_sp(sp3);
  }
  h2v g3p[16];
  #pragma unroll
  for (int q = 0; q < 15; q++) g3p[q] = mkh2(g3[2*q], g3[2*q+1]);
  g3p[15] = mkh2(0.f, 0.f);
  #pragma unroll
  for (int q = 0; q < 15; q++){
    uint4 a = sPM3C[2*q], b = sPM3C[2*q+1];
    ac[0] = dot2(uh(a.x), g3p[q], ac[0]);
    ac[1] = dot2(uh(a.y), g3p[q], ac[1]);
    ac[2] = dot2(uh(a.z), g3p[q], ac[2]);
    ac[3] = dot2(uh(a.w), g3p[q], ac[3]);
    ac[4] = dot2(uh(b.x), g3p[q], ac[4]);
    ac[5] = dot2(uh(b.y), g3p[q], ac[5]);
  }

  // ============ bwd g2 (slot order; runtime-row weight reads) ============
  uint g2p[32];
  #pragma unroll
  for (int s = 0; s < 32; s++){
    const int mm = (s>>3)&1, rp = s&7;
    const int pb = 2*(rp&1) + 8*(rp>>1);
    int rowb = mm*32 + pb + ((s < 16) ? 4*hh : 4-4*hh);
    const uint4* r0p = sPI3C + rowb*4;
    const uint4* r1p = r0p + 4;
    float ta = 0.0f, tb = 0.0f;
    #pragma unroll
    for (int q4 = 0; q4 < 4; q4++){
      uint4 v0 = r0p[q4], v1 = r1p[q4];
      ta = dot2(uh(v0.x), g3p[4*q4+0], ta);
      ta = dot2(uh(v0.y), g3p[4*q4+1], ta);
      ta = dot2(uh(v0.z), g3p[4*q4+2], ta);
      ta = dot2(uh(v0.w), g3p[4*q4+3], ta);
      tb = dot2(uh(v1.x), g3p[4*q4+0], tb);
      tb = dot2(uh(v1.y), g3p[4*q4+1], tb);
      tb = dot2(uh(v1.z), g3p[4*q4+2], tb);
      tb = dot2(uh(v1.w), g3p[4*q4+3], tb);
    }
    h2v sp = uh(c2p[s]);
    ta *= sig_from_sp((float)sp.x);
    tb *= sig_from_sp((float)sp.y);
    h2v tp = mkh2(ta, tb);
    g2p[s] = __builtin_bit_cast(uint, tp);
    int jp = rowb >> 1;
    uint4 a = sPM2C[jp*2], b = sPM2C[jp*2+1];
    ac[0] = dot2(uh(a.x), tp, ac[0]);
    ac[1] = dot2(uh(a.y), tp, ac[1]);
    ac[2] = dot2(uh(a.z), tp, ac[2]);
    ac[3] = dot2(uh(a.w), tp, ac[3]);
    ac[4] = dot2(uh(b.x), tp, ac[4]);
    ac[5] = dot2(uh(b.y), tp, ac[5]);
  }

  // ============ bwd g1 (z1 recomputed; slot-addressed W2^T reads) ============
  #pragma unroll
  for (int p = 0; p < 30; p++){
    uint4 wA = sPI1B[2*p], wB = sPI1B[2*p+1];
    float za = uf(wA.w), zb = uf(wB.w);
    za = dot2(uh(wA.x), xp[0], za); za = dot2(uh(wA.y), xp[1], za); za = dot2(uh(wA.z), xp[2], za);
    zb = dot2(uh(wB.x), xp[0], zb); zb = dot2(uh(wB.y), xp[1], zb); zb = dot2(uh(wB.z), xp[2], zb);
    const uint* r0 = sPI2Cu + (2*p)*32;
    const uint* r1 = r0 + 32;
    float ta = 0.0f, tb = 0.0f;
    #pragma unroll
    for (int m = 0; m < 2; m++){
      #pragma unroll
      for (int rg = 0; rg < 4; rg++){
        const int o = m*16 + rg*4;
        uint2 v0o = *(const uint2*)(r0 + o + 2*hh);
        uint2 v1o = *(const uint2*)(r1 + o + 2*hh);
        ta = dot2(uh(v0o.x), uh(g2p[m*8+2*rg]),   ta);
        ta = dot2(uh(v0o.y), uh(g2p[m*8+2*rg+1]), ta);
        tb = dot2(uh(v1o.x), uh(g2p[m*8+2*rg]),   tb);
        tb = dot2(uh(v1o.y), uh(g2p[m*8+2*rg+1]), tb);
        uint2 v0p = *(const uint2*)(r0 + o + 2 - 2*hh);
        uint2 v1p = *(const uint2*)(r1 + o + 2 - 2*hh);
        ta = dot2(uh(v0p.x), uh(g2p[16+m*8+2*rg]),   ta);
        ta = dot2(uh(v0p.y), uh(g2p[16+m*8+2*rg+1]), ta);
        tb = dot2(uh(v1p.x), uh(g2p[16+m*8+2*rg]),   tb);
        tb = dot2(uh(v1p.y), uh(g2p[16+m*8+2*rg+1]), tb);
      }
    }
    ta *= fast_sig(za); tb *= fast_sig(zb);
    h2v tp = mkh2(ta, tb);
    uint4 a = sPI1C[2*p], b = sPI1C[2*p+1];
    ac[0] = dot2(uh(a.x), tp, ac[0]);
    ac[1] = dot2(uh(a.y), tp, ac[1]);
    ac[2] = dot2(uh(a.z), tp, ac[2]);
    ac[3] = dot2(uh(a.w), tp, ac[3]);
    ac[4] = dot2(uh(b.x), tp, ac[4]);
    ac[5] = dot2(uh(b.y), tp, ac[5]);
  }

  // ============ V, dV ============
  float hdiff = y - sYREF;
  float sigma = (hdiff >= 1.0f) ? (hdiff - 0.5f) : ((hdiff > 0.0f) ? 0.5f*hdiff*hdiff : 0.0f);
  float sigp  = (hdiff >= 1.0f) ? 1.0f          : ((hdiff > 0.0f) ? hdiff             : 0.0f);
  float dx2 = 0.0f;
  float dV[6];
  #pragma unroll
  for (int d = 0; d < 6; d++){
    float dx = x[d] - sXREF[d];
    dx2 = fmaf(dx, dx, dx2);
    dV[d] = fmaf(sigp, ac[d], 2.0f*EPS*dx);
  }
  float V = sigma + EPS*dx2;

  float sc = ALPHA * V;
  #pragma unroll
  for (int d = 0; d < 6; d++) sc = fmaf(dV[d], f[d], sc);

  // ============ GNN + combine ============
  float u[6];
  #pragma unroll
  for (int m = 0; m < 6; m++) u[m] = valid ? U[(long)i*6 + m] : 0.0f;
  float am[6] = {0.f,0.f,0.f,0.f,0.f,0.f};
  float gU[6];
  #pragma unroll
  for (int d = 0; d < 6; d++){
    float acc = 0.0f;
    #pragma unroll
    for (int m = 0; m < 6; m++){
      int o = d*6 + m;
      uint4 g4 = sPGB[o];
      float g = uf(g4.w);
      g = dot2(uh(g4.x), xp[0], g); g = dot2(uh(g4.y), xp[1], g); g = dot2(uh(g4.z), xp[2], g);
      am[m] = fmaf(dV[d], g, am[m]);
      acc   = fmaf(g, u[m], acc);
    }
    gU[d] = acc;
  }
  #pragma unroll
  for (int m = 0; m < 6; m++) sc -= fabsf(am[m]);

  float n2 = 0.0f;
  #pragma unroll
  for (int d = 0; d < 6; d++) n2 = fmaf(dV[d], dV[d], n2);
  float r = fmaxf(sc, 0.0f) * rcp_f(n2);

  if (valid){
    #pragma unroll
    for (int d = 0; d < 6; d++)
      out[(long)i*6 + d] = f[d] - dV[d]*r + gU[d];
  }
}

extern "C" void kernel_launch(void* const* d_in, const int* in_sizes, int n_in,
                              void* d_out, int out_size, void* d_ws, size_t ws_size,
                              hipStream_t stream)
{
  const float* X    = (const float*)d_in[0];
  const float* U    = (const float*)d_in[1];
  const float* xref = (const float*)d_in[2];
  const float* fw1  = (const float*)d_in[3];
  const float* fb1  = (const float*)d_in[4];
  const float* fw2  = (const float*)d_in[5];
  const float* fb2  = (const float*)d_in[6];
  const float* fw3  = (const float*)d_in[7];
  const float* fb3  = (const float*)d_in[8];
  const float* gw   = (const float*)d_in[9];
  const float* gb   = (const float*)d_in[10];
  const float* iw1  = (const float*)d_in[11];
  const float* ib1  = (const float*)d_in[12];
  const float* iw2  = (const float*)d_in[13];
  const float* ib2  = (const float*)d_in[14];
  const float* iw3  = (const float*)d_in[15];
  const float* ib3  = (const float*)d_in[16];
  const float* iw4  = (const float*)d_in[17];
  const float* ib4  = (const float*)d_in[18];
  const float* im2  = (const float*)d_in[19];
  const float* im3  = (const float*)d_in[20];
  const float* im4  = (const float*)d_in[21];

  float* out = (float*)d_out;
  int N = in_sizes[0] / 6;

  int threads = 512;
  int blocks  = (N + threads - 1) / threads;
  holo_main<<<blocks, threads, 0, stream>>>(X, U, xref,
      fw1, fb1, fw2, fb2, fw3, fb3, gw, gb,
      iw1, ib1, iw2, ib2, iw3, ib3, iw4, ib4, im2, im3, im4,
      out, N);
}

// Round 8
// 1923.730 us; speedup vs baseline: 1.0487x; 1.0487x over previous
//
#include <hip/hip_runtime.h>

#define EPS 1e-05f
#define ALPHA 0.05f

typedef _Float16 h2v __attribute__((ext_vector_type(2)));
typedef _Float16 f16x8 __attribute__((ext_vector_type(8)));
typedef float f32x16 __attribute__((ext_vector_type(16)));

__device__ __forceinline__ float rcp_f(float x){ return __builtin_amdgcn_rcpf(x); }
__device__ __forceinline__ float dot2(h2v a, h2v b, float c){
  return __builtin_amdgcn_fdot2(a, b, c, false);
}
__device__ __forceinline__ h2v uh(uint u){ return __builtin_bit_cast(h2v, u); }
__device__ __forceinline__ float uf(uint u){ return __builtin_bit_cast(float, u); }

#define LOG2E 1.4426950408889634f
#define LN2   0.6931471805599453f

__device__ __forceinline__ float fast_tanh(float x){
  float ax = fabsf(x);
  float e  = exp2f(ax * (-2.0f * LOG2E));
  float t  = (1.0f - e) * rcp_f(1.0f + e);
  return copysignf(t, x);
}
__device__ __forceinline__ float fast_sp(float x){
  float ax = fabsf(x);
  float e  = exp2f(ax * -LOG2E);
  return fmaxf(x, 0.0f) + log2f(1.0f + e) * LN2;
}
__device__ __forceinline__ float fast_sig(float x){
  float ax = fabsf(x);
  float e  = exp2f(ax * -LOG2E);
  float r  = rcp_f(1.0f + e);
  return x >= 0.0f ? r : e * r;
}
__device__ __forceinline__ float sig_from_sp(float sp){
  return 1.0f - exp2f(sp * -LOG2E);
}
__device__ __forceinline__ h2v mkh2(float a, float b){
  h2v r; r.x = (_Float16)a; r.y = (_Float16)b; return r;
}
__device__ __forceinline__ uint packh(float a, float b){
  ushort lo = __builtin_bit_cast(ushort, (_Float16)a);
  ushort hi = __builtin_bit_cast(ushort, (_Float16)b);
  return (uint)lo | ((uint)hi << 16);
}
__device__ __forceinline__ float f16lo(uint u){
  return (float)__builtin_bit_cast(_Float16, (ushort)(u & 0xffffu));
}
__device__ __forceinline__ float f16hi(uint u){
  return (float)__builtin_bit_cast(_Float16, (ushort)(u >> 16));
}

// ================= fused kernel: stage + pack + yref + compute =================
__global__ __launch_bounds__(512, 2) void holo_main(
    const float* __restrict__ X, const float* __restrict__ U,
    const float* __restrict__ xref,
    const float* __restrict__ fw1, const float* __restrict__ fb1,
    const float* __restrict__ fw2, const float* __restrict__ fb2,
    const float* __restrict__ fw3, const float* __restrict__ fb3,
    const float* __restrict__ gw,  const float* __restrict__ gb,
    const float* __restrict__ iw1, const float* __restrict__ ib1,
    const float* __restrict__ iw2, const float* __restrict__ ib2,
    const float* __restrict__ iw3, const float* __restrict__ ib3,
    const float* __restrict__ iw4, const float* __restrict__ ib4,
    const float* __restrict__ im2, const float* __restrict__ im3,
    const float* __restrict__ im4,
    float* __restrict__ out, int N)
{
  // ---- LDS (natural layouts, zero-padded; reads use runtime hh offsets) ----
  __shared__ alignas(16) ushort sW2r[224*84]; // fw2 MFMA-A [224 rows][84 halves]
  __shared__ uint4 sW3E[224];   // 112 n-pairs x2: {w3 d0..d5 pairs, fb2[n], fb2[n+1]}
  __shared__ alignas(16) ushort sA2[64*68];   // iw2 MFMA-A [64 rows j][68 halves k]
  __shared__ uint4 sPW1B[80];   // fw1 row o: {w01,w23,w45, fb1[o]}
  __shared__ uint4 sPGB[36];    // gw  row o: {w01,w23,w45, gb[o]}
  __shared__ uint4 sPI1B[60];   // iw1 rows: {w,b} pairs
  __shared__ uint4 sPI1C[60];   // iw1^T pairs [30 kp][6 d + pad]
  __shared__ uint4 sPI3[240];   // iw3 [30 i3][32 jp] (jp 30,31 = 0)
  __shared__ uint4 sPI3C[256];  // iw3^T [64 j][16 qp] (rows 60-63, qp 15 = 0)
  __shared__ uint4 sPM2B[64];   // im2 row j: {w01,w23,w45, ib2[j]} (rows 60-63 = 0)
  __shared__ uint4 sPM2C[64];   // im2^T [32 jp][8] (jp 30,31 = 0)
  __shared__ uint4 sPM3B[60];   // im3 rows: {w,ib3 | iw4,0,0,0}
  __shared__ uint4 sPM3C[30];   // im3^T [15 qp][8]
  __shared__ uint  sPM4u[4];    // im4 pairs
  __shared__ alignas(16) uint sPI2Cu[60*32]; // iw2^T [60 k1][32 jp] (jp 30,31 = 0)
  __shared__ float sFB3[6], sXREF[6], sIM4[6];
  __shared__ float sS1[60], sS2[60], sS3[30];
  __shared__ float sYREF, sIB4;

  const int t = threadIdx.x;
  const int T = 512;
  const int lane = t & 63;
  const int hh  = lane >> 5;
  const int l31 = lane & 31;

  // ---- stage + pack from original weights ----
  for (int idx=t; idx<224*42; idx+=T){
    int row = idx/42, c = idx%42, k = 2*c;
    uint v = 0;
    if (row < 200 && k < 80) v = packh(fw2[row*80+k], fw2[row*80+k+1]);
    ((uint*)sW2r)[idx] = v;
  }
  for (int idx=t; idx<896; idx+=T){
    int P = idx/8, c = idx%8, n = 2*P;
    uint v = 0;
    if (n < 200){
      if (c < 6)       v = packh(fw3[c*200+n], fw3[c*200+n+1]);
      else if (c == 6) v = __builtin_bit_cast(uint, fb2[n]);
      else             v = __builtin_bit_cast(uint, fb2[n+1]);
    }
    ((uint*)sW3E)[idx] = v;
  }
  for (int idx=t; idx<64*34; idx+=T){           // sA2
    int row = idx/34, c = idx%34, k = 2*c;
    uint v = 0;
    if (row < 60 && c < 30) v = packh(iw2[row*60+k], iw2[row*60+k+1]);
    ((uint*)sA2)[idx] = v;
  }
  for (int idx=t; idx<320; idx+=T){
    int o = idx/4, c = idx%4;
    ((uint*)sPW1B)[idx] = (c<3) ? packh(fw1[o*6+2*c], fw1[o*6+2*c+1])
                                : __builtin_bit_cast(uint, fb1[o]);
  }
  for (int idx=t; idx<144; idx+=T){
    int o = idx/4, c = idx%4;
    ((uint*)sPGB)[idx] = (c<3) ? packh(gw[o*6+2*c], gw[o*6+2*c+1])
                               : __builtin_bit_cast(uint, gb[o]);
  }
  for (int idx=t; idx<240; idx+=T){
    int p = idx/8, c = idx%8, sub = c/4, cc = c%4, nr = 2*p+sub;
    ((uint*)sPI1B)[idx] = (cc<3) ? packh(iw1[nr*6+2*cc], iw1[nr*6+2*cc+1])
                                 : __builtin_bit_cast(uint, ib1[nr]);
  }
  for (int idx=t; idx<240; idx+=T){
    int q = idx/8, c = idx%8;
    ((uint*)sPI1C)[idx] = (c<6) ? packh(iw1[(2*q)*6+c], iw1[(2*q+1)*6+c]) : 0u;
  }
  for (int idx=t; idx<960; idx+=T){
    int r = idx/32, q = idx%32;
    ((uint*)sPI3)[idx] = (q<30) ? packh(iw3[r*60+2*q], iw3[r*60+2*q+1]) : 0u;
  }
  for (int idx=t; idx<1024; idx+=T){
    int j = idx/16, q = idx%16;
    ((uint*)sPI3C)[idx] = (j<60 && q<15) ? packh(iw3[(2*q)*60+j], iw3[(2*q+1)*60+j]) : 0u;
  }
  for (int idx=t; idx<256; idx+=T){
    int j = idx/4, c = idx%4;
    uint v = 0;
    if (j < 60) v = (c<3) ? packh(im2[j*6+2*c], im2[j*6+2*c+1])
                          : __builtin_bit_cast(uint, ib2[j]);
    ((uint*)sPM2B)[idx] = v;
  }
  for (int idx=t; idx<256; idx+=T){
    int q = idx/8, c = idx%8;
    ((uint*)sPM2C)[idx] = (q<30 && c<6) ? packh(im2[(2*q)*6+c], im2[(2*q+1)*6+c]) : 0u;
  }
  for (int idx=t; idx<240; idx+=T){
    int r = idx/8, c = idx%8;
    uint v = 0;
    if (c < 3)       v = packh(im3[r*6+2*c], im3[r*6+2*c+1]);
    else if (c == 3) v = __builtin_bit_cast(uint, ib3[r]);
    else if (c == 4) v = __builtin_bit_cast(uint, iw4[r]);
    ((uint*)sPM3B)[idx] = v;
  }
  for (int idx=t; idx<120; idx+=T){
    int q = idx/8, c = idx%8;
    ((uint*)sPM3C)[idx] = (c<6) ? packh(im3[(2*q)*6+c], im3[(2*q+1)*6+c]) : 0u;
  }
  for (int idx=t; idx<4; idx+=T)
    sPM4u[idx] = (idx<3) ? packh(im4[2*idx], im4[2*idx+1]) : 0u;
  for (int idx=t; idx<1920; idx+=T){
    int k1 = idx/32, q = idx%32;
    sPI2Cu[idx] = (q<30) ? packh(iw2[(2*q)*60+k1], iw2[(2*q+1)*60+k1]) : 0u;
  }
  for (int k=t;k<6;k+=T){ sFB3[k]=fb3[k]; sIM4[k]=im4[k]; sXREF[k]=xref[k]; }
  if (t==0) sIB4=ib4[0];
  __syncthreads();

  // ---- cooperative yref = icnn(xref) from the SAME packed f16 weights ----
  {
    h2v xrp[3];
    #pragma unroll
    for (int p = 0; p < 3; p++) xrp[p] = mkh2(sXREF[2*p], sXREF[2*p+1]);
    if (t < 60){
      const uint* w = (const uint*)sPI1B + (t/2)*8 + (t&1)*4;
      float z = uf(w[3]);
      #pragma unroll
      for (int c = 0; c < 3; c++) z = dot2(uh(w[c]), xrp[c], z);
      sS1[t] = fast_sp(z);
    }
    __syncthreads();
    if (t < 60){
      const uint* m = (const uint*)sPM2B + t*4;
      float z = uf(m[3]);
      #pragma unroll
      for (int c = 0; c < 3; c++) z = dot2(uh(m[c]), xrp[c], z);
      const uint* arow = (const uint*)sA2 + t*34;
      for (int q = 0; q < 30; q++)
        z = dot2(uh(arow[q]), mkh2(sS1[2*q], sS1[2*q+1]), z);
      sS2[t] = fast_sp(z);
    }
    __syncthreads();
    if (t < 30){
      const uint* m = (const uint*)sPM3B + t*8;
      float z = uf(m[3]);
      #pragma unroll
      for (int c = 0; c < 3; c++) z = dot2(uh(m[c]), xrp[c], z);
      const uint* prow = (const uint*)sPI3 + t*32;
      for (int q = 0; q < 30; q++)
        z = dot2(uh(prow[q]), mkh2(sS2[2*q], sS2[2*q+1]), z);
      sS3[t] = fast_sp(z);
    }
    __syncthreads();
    if (t == 0){
      float y = sIB4;
      #pragma unroll
      for (int p = 0; p < 3; p++) y = dot2(uh(sPM4u[p]), xrp[p], y);
      for (int j = 0; j < 30; j++) y = fmaf(uf(((const uint*)sPM3B)[j*8+4]), sS3[j], y);
      sYREF = y;
    }
    __syncthreads();
  }

  // ---- per-thread sample compute (guarded loads/stores, full-wave execution) ----
  const int i = blockIdx.x * blockDim.x + t;
  const bool valid = (i < N);

  float x[6]; h2v xp[3];
  #pragma unroll
  for (int k = 0; k < 6; k++) x[k] = valid ? X[(long)i*6 + k] : 0.0f;
  #pragma unroll
  for (int p = 0; p < 3; p++) xp[p] = mkh2(x[2*p], x[2*p+1]);

  // ============ FNN layer 1: 6 -> 80, tanh ============
  uint h1u[40];
  #pragma unroll
  for (int o = 0; o < 80; o += 2){
    uint4 wa = sPW1B[o], wb = sPW1B[o+1];
    float z0 = uf(wa.w), z1 = uf(wb.w);
    z0 = dot2(uh(wa.x), xp[0], z0); z0 = dot2(uh(wa.y), xp[1], z0); z0 = dot2(uh(wa.z), xp[2], z0);
    z1 = dot2(uh(wb.x), xp[0], z1); z1 = dot2(uh(wb.y), xp[1], z1); z1 = dot2(uh(wb.z), xp[2], z1);
    h1u[o/2] = packh(fast_tanh(z0), fast_tanh(z1));
  }

  // ============ FNN L2+L3 via MFMA (32x32x16 f16) ============
  uint bf0[5][4], bf1[5][4];
  {
    int a0 = 4 * l31;
    int a1 = 4 * (32 + l31);
    #pragma unroll
    for (int kt = 0; kt < 5; kt++){
      #pragma unroll
      for (int q = 0; q < 4; q++){
        int lo0 = __builtin_amdgcn_ds_bpermute(a0, (int)h1u[kt*8 + q]);
        int hi0 = __builtin_amdgcn_ds_bpermute(a0, (int)h1u[kt*8 + 4 + q]);
        bf0[kt][q] = hh ? (uint)hi0 : (uint)lo0;
        int lo1 = __builtin_amdgcn_ds_bpermute(a1, (int)h1u[kt*8 + q]);
        int hi1 = __builtin_amdgcn_ds_bpermute(a1, (int)h1u[kt*8 + 4 + q]);
        bf1[kt][q] = hh ? (uint)hi1 : (uint)lo1;
      }
    }
  }

  float fp0[6] = {0.f,0.f,0.f,0.f,0.f,0.f};
  float fp1[6] = {0.f,0.f,0.f,0.f,0.f,0.f};
  for (int mt = 0; mt < 7; mt++){
    const int row = mt*32 + l31;
    f16x8 af[5];
    #pragma unroll
    for (int kt = 0; kt < 5; kt++){
      const ushort* wp = &sW2r[row*84 + kt*16 + 8*hh];
      uint2 w0 = *(const uint2*)wp;
      uint2 w1 = *(const uint2*)(wp + 4);
      uint4 au; au.x = w0.x; au.y = w0.y; au.z = w1.x; au.w = w1.y;
      af[kt] = __builtin_bit_cast(f16x8, au);
    }
    f32x16 acc0 = {0,0,0,0,0,0,0,0,0,0,0,0,0,0,0,0};
    f32x16 acc1 = {0,0,0,0,0,0,0,0,0,0,0,0,0,0,0,0};
    #pragma unroll
    for (int kt = 0; kt < 5; kt++){
      uint4 b0u; b0u.x=bf0[kt][0]; b0u.y=bf0[kt][1]; b0u.z=bf0[kt][2]; b0u.w=bf0[kt][3];
      uint4 b1u; b1u.x=bf1[kt][0]; b1u.y=bf1[kt][1]; b1u.z=bf1[kt][2]; b1u.w=bf1[kt][3];
      acc0 = __builtin_amdgcn_mfma_f32_32x32x16_f16(af[kt], __builtin_bit_cast(f16x8, b0u), acc0, 0, 0, 0);
      acc1 = __builtin_amdgcn_mfma_f32_32x32x16_f16(af[kt], __builtin_bit_cast(f16x8, b1u), acc1, 0, 0, 0);
    }
    // epilogue (neuron pairs); rows 200-223 are zero-pad -> mt==6 keeps only c==0
    #pragma unroll
    for (int c = 0; c < 4; c++){
      #pragma unroll
      for (int b0h = 0; b0h < 2; b0h++){
        if (mt == 6 && c > 0) continue;
        const int r0 = 4*c + 2*b0h;
        const int P  = mt*16 + 4*c + 2*hh + b0h;
        uint4 wa = sW3E[P*2], wb = sW3E[P*2+1];
        float bA = uf(wb.z), bB = uf(wb.w);
        h2v tp0 = mkh2(fast_tanh(acc0[r0] + bA), fast_tanh(acc0[r0+1] + bB));
        h2v tp1 = mkh2(fast_tanh(acc1[r0] + bA), fast_tanh(acc1[r0+1] + bB));
        fp0[0] = dot2(uh(wa.x), tp0, fp0[0]); fp1[0] = dot2(uh(wa.x), tp1, fp1[0]);
        fp0[1] = dot2(uh(wa.y), tp0, fp0[1]); fp1[1] = dot2(uh(wa.y), tp1, fp1[1]);
        fp0[2] = dot2(uh(wa.z), tp0, fp0[2]); fp1[2] = dot2(uh(wa.z), tp1, fp1[2]);
        fp0[3] = dot2(uh(wa.w), tp0, fp0[3]); fp1[3] = dot2(uh(wa.w), tp1, fp1[3]);
        fp0[4] = dot2(uh(wb.x), tp0, fp0[4]); fp1[4] = dot2(uh(wb.x), tp1, fp1[4]);
        fp0[5] = dot2(uh(wb.y), tp0, fp0[5]); fp1[5] = dot2(uh(wb.y), tp1, fp1[5]);
      }
    }
  }
  float f[6];
  #pragma unroll
  for (int d = 0; d < 6; d++){
    float s0 = fp0[d] + __shfl_xor(fp0[d], 32, 64);
    float s1 = fp1[d] + __shfl_xor(fp1[d], 32, 64);
    f[d] = sFB3[d] + (hh ? s1 : s0);
  }

  // ============ ICNN z1 -> sp1 packed ============
  uint sp1p[32];
  #pragma unroll
  for (int p = 0; p < 30; p++){
    uint4 wA = sPI1B[2*p], wB = sPI1B[2*p+1];
    float za = uf(wA.w), zb = uf(wB.w);
    za = dot2(uh(wA.x), xp[0], za); za = dot2(uh(wA.y), xp[1], za); za = dot2(uh(wA.z), xp[2], za);
    zb = dot2(uh(wB.x), xp[0], zb); zb = dot2(uh(wB.y), xp[1], zb); zb = dot2(uh(wB.z), xp[2], zb);
    sp1p[p] = packh(fast_sp(za), fast_sp(zb));
  }
  sp1p[30] = 0u; sp1p[31] = 0u;

  // ============ z2 = W2*sp1 via MFMA (split by m-half to cap live regs) ======
  uint zbf0[4][4], zbf1[4][4];
  {
    int a0 = 4 * l31;
    int a1 = 4 * (32 + l31);
    #pragma unroll
    for (int kt = 0; kt < 4; kt++){
      #pragma unroll
      for (int q = 0; q < 4; q++){
        int lo0 = __builtin_amdgcn_ds_bpermute(a0, (int)sp1p[kt*8 + q]);
        int hi0 = __builtin_amdgcn_ds_bpermute(a0, (int)sp1p[kt*8 + 4 + q]);
        zbf0[kt][q] = hh ? (uint)hi0 : (uint)lo0;
        int lo1 = __builtin_amdgcn_ds_bpermute(a1, (int)sp1p[kt*8 + q]);
        int hi1 = __builtin_amdgcn_ds_bpermute(a1, (int)sp1p[kt*8 + 4 + q]);
        zbf1[kt][q] = hh ? (uint)hi1 : (uint)lo1;
      }
    }
  }
  // sp1p dead from here; per-half accumulators keep peak pressure ~115 regs.
  uint c2p[32];
  #pragma unroll
  for (int m = 0; m < 2; m++){
    f16x8 af[4];
    #pragma unroll
    for (int kt = 0; kt < 4; kt++){
      const ushort* wp = &sA2[(m*32+l31)*68 + kt*16 + 8*hh];
      uint2 w0 = *(const uint2*)wp;
      uint2 w1 = *(const uint2*)(wp + 4);
      uint4 au; au.x = w0.x; au.y = w0.y; au.z = w1.x; au.w = w1.y;
      af[kt] = __builtin_bit_cast(f16x8, au);
    }
    f32x16 za0 = {0,0,0,0,0,0,0,0,0,0,0,0,0,0,0,0};
    f32x16 za1 = {0,0,0,0,0,0,0,0,0,0,0,0,0,0,0,0};
    #pragma unroll
    for (int kt = 0; kt < 4; kt++){
      uint4 b0u; b0u.x=zbf0[kt][0]; b0u.y=zbf0[kt][1]; b0u.z=zbf0[kt][2]; b0u.w=zbf0[kt][3];
      uint4 b1u; b1u.x=zbf1[kt][0]; b1u.y=zbf1[kt][1]; b1u.z=zbf1[kt][2]; b1u.w=zbf1[kt][3];
      za0 = __builtin_amdgcn_mfma_f32_32x32x16_f16(af[kt], __builtin_bit_cast(f16x8, b0u), za0, 0, 0, 0);
      za1 = __builtin_amdgcn_mfma_f32_32x32x16_f16(af[kt], __builtin_bit_cast(f16x8, b1u), za1, 0, 0, 0);
    }
    // exchange the partner-half rows (send opposite-nt, f16-packed)
    uint ru[8];
    #pragma unroll
    for (int rp = 0; rp < 8; rp++){
      float s0 = hh ? za0[2*rp]   : za1[2*rp];
      float s1 = hh ? za0[2*rp+1] : za1[2*rp+1];
      ru[rp] = (uint)__shfl_xor((int)packh(s0, s1), 32, 64);
    }
    // assemble this half's c2p slots: [own | partner]
    #pragma unroll
    for (int rp = 0; rp < 8; rp++){
      const int pb = 2*(rp&1) + 8*(rp>>1);
      int rowb = m*32 + pb + 4*hh;
      uint4 i0 = sPM2B[rowb], i1 = sPM2B[rowb+1];
      float zlo = uf(i0.w) + (hh ? za1[2*rp]   : za0[2*rp]);
      float zhi = uf(i1.w) + (hh ? za1[2*rp+1] : za0[2*rp+1]);
      zlo = dot2(uh(i0.x), xp[0], zlo); zlo = dot2(uh(i0.y), xp[1], zlo); zlo = dot2(uh(i0.z), xp[2], zlo);
      zhi = dot2(uh(i1.x), xp[0], zhi); zhi = dot2(uh(i1.y), xp[1], zhi); zhi = dot2(uh(i1.z), xp[2], zhi);
      c2p[m*8+rp] = packh(fast_sp(zlo), fast_sp(zhi));
      int rowb2 = m*32 + pb + 4 - 4*hh;
      uint4 j0 = sPM2B[rowb2], j1 = sPM2B[rowb2+1];
      float plo = uf(j0.w) + f16lo(ru[rp]);
      float phi = uf(j1.w) + f16hi(ru[rp]);
      plo = dot2(uh(j0.x), xp[0], plo); plo = dot2(uh(j0.y), xp[1], plo); plo = dot2(uh(j0.z), xp[2], plo);
      phi = dot2(uh(j1.x), xp[0], phi); phi = dot2(uh(j1.y), xp[1], phi); phi = dot2(uh(j1.z), xp[2], phi);
      c2p[16+m*8+rp] = packh(fast_sp(plo), fast_sp(phi));
    }
  }

  // ============ z3 fwd + y + g3 (slot-addressed weight reads) ============
  float y = sIB4;
  #pragma unroll
  for (int p = 0; p < 3; p++) y = dot2(uh(sPM4u[p]), xp[p], y);
  float ac[6];
  #pragma unroll
  for (int d = 0; d < 6; d++) ac[d] = sIM4[d];
  h2v g3p[16];
  float g3even;
  #pragma unroll
  for (int i3 = 0; i3 < 30; i3++){
    uint4 m0 = sPM3B[2*i3], m1 = sPM3B[2*i3+1];
    float z = uf(m0.w);
    z = dot2(uh(m0.x), xp[0], z); z = dot2(uh(m0.y), xp[1], z); z = dot2(uh(m0.z), xp[2], z);
    const uint* prow = (const uint*)sPI3 + i3*32;
    #pragma unroll
    for (int m = 0; m < 2; m++){
      #pragma unroll
      for (int rg = 0; rg < 4; rg++){
        const int o = m*16 + rg*4;
        uint2 vo = *(const uint2*)(prow + o + 2*hh);
        z = dot2(uh(vo.x), uh(c2p[m*8+2*rg]),   z);
        z = dot2(uh(vo.y), uh(c2p[m*8+2*rg+1]), z);
        uint2 vp = *(const uint2*)(prow + o + 2 - 2*hh);
        z = dot2(uh(vp.x), uh(c2p[16+m*8+2*rg]),   z);
        z = dot2(uh(vp.y), uh(c2p[16+m*8+2*rg+1]), z);
      }
    }
    float sp3 = fast_sp(z);
    float w4  = uf(m1.x);
    y = fmaf(w4, sp3, y);
    float gi = w4 * sig_from_sp(sp3);
    if (i3 & 1) g3p[i3>>1] = mkh2(g3even, gi); else g3even = gi;
  }
  g3p[15] = mkh2(0.f, 0.f);
  #pragma unroll
  for (int q = 0; q < 15; q++){
    uint4 a = sPM3C[2*q], b = sPM3C[2*q+1];
    ac[0] = dot2(uh(a.x), g3p[q], ac[0]);
    ac[1] = dot2(uh(a.y), g3p[q], ac[1]);
    ac[2] = dot2(uh(a.z), g3p[q], ac[2]);
    ac[3] = dot2(uh(a.w), g3p[q], ac[3]);
    ac[4] = dot2(uh(b.x), g3p[q], ac[4]);
    ac[5] = dot2(uh(b.y), g3p[q], ac[5]);
  }

  // ============ bwd g2 (slot order; runtime-row weight reads) ============
  uint g2p[32];
  #pragma unroll
  for (int s = 0; s < 32; s++){
    const int mm = (s>>3)&1, rp = s&7;
    const int pb = 2*(rp&1) + 8*(rp>>1);
    int rowb = mm*32 + pb + ((s < 16) ? 4*hh : 4-4*hh);
    const uint4* r0p = sPI3C + rowb*4;
    const uint4* r1p = r0p + 4;
    float ta = 0.0f, tb = 0.0f;
    #pragma unroll
    for (int q4 = 0; q4 < 4; q4++){
      uint4 v0 = r0p[q4], v1 = r1p[q4];
      ta = dot2(uh(v0.x), g3p[4*q4+0], ta);
      ta = dot2(uh(v0.y), g3p[4*q4+1], ta);
      ta = dot2(uh(v0.z), g3p[4*q4+2], ta);
      ta = dot2(uh(v0.w), g3p[4*q4+3], ta);
      tb = dot2(uh(v1.x), g3p[4*q4+0], tb);
      tb = dot2(uh(v1.y), g3p[4*q4+1], tb);
      tb = dot2(uh(v1.z), g3p[4*q4+2], tb);
      tb = dot2(uh(v1.w), g3p[4*q4+3], tb);
    }
    h2v sp = uh(c2p[s]);
    ta *= sig_from_sp((float)sp.x);
    tb *= sig_from_sp((float)sp.y);
    h2v tp = mkh2(ta, tb);
    g2p[s] = __builtin_bit_cast(uint, tp);
    int jp = rowb >> 1;
    uint4 a = sPM2C[jp*2], b = sPM2C[jp*2+1];
    ac[0] = dot2(uh(a.x), tp, ac[0]);
    ac[1] = dot2(uh(a.y), tp, ac[1]);
    ac[2] = dot2(uh(a.z), tp, ac[2]);
    ac[3] = dot2(uh(a.w), tp, ac[3]);
    ac[4] = dot2(uh(b.x), tp, ac[4]);
    ac[5] = dot2(uh(b.y), tp, ac[5]);
  }

  // ============ bwd g1 (z1 recomputed; slot-addressed W2^T reads) ============
  #pragma unroll
  for (int p = 0; p < 30; p++){
    uint4 wA = sPI1B[2*p], wB = sPI1B[2*p+1];
    float za = uf(wA.w), zb = uf(wB.w);
    za = dot2(uh(wA.x), xp[0], za); za = dot2(uh(wA.y), xp[1], za); za = dot2(uh(wA.z), xp[2], za);
    zb = dot2(uh(wB.x), xp[0], zb); zb = dot2(uh(wB.y), xp[1], zb); zb = dot2(uh(wB.z), xp[2], zb);
    const uint* r0 = sPI2Cu + (2*p)*32;
    const uint* r1 = r0 + 32;
    float ta = 0.0f, tb = 0.0f;
    #pragma unroll
    for (int m = 0; m < 2; m++){
      #pragma unroll
      for (int rg = 0; rg < 4; rg++){
        const int o = m*16 + rg*4;
        uint2 v0o = *(const uint2*)(r0 + o + 2*hh);
        uint2 v1o = *(const uint2*)(r1 + o + 2*hh);
        ta = dot2(uh(v0o.x), uh(g2p[m*8+2*rg]),   ta);
        ta = dot2(uh(v0o.y), uh(g2p[m*8+2*rg+1]), ta);
        tb = dot2(uh(v1o.x), uh(g2p[m*8+2*rg]),   tb);
        tb = dot2(uh(v1o.y), uh(g2p[m*8+2*rg+1]), tb);
        uint2 v0p = *(const uint2*)(r0 + o + 2 - 2*hh);
        uint2 v1p = *(const uint2*)(r1 + o + 2 - 2*hh);
        ta = dot2(uh(v0p.x), uh(g2p[16+m*8+2*rg]),   ta);
        ta = dot2(uh(v0p.y), uh(g2p[16+m*8+2*rg+1]), ta);
        tb = dot2(uh(v1p.x), uh(g2p[16+m*8+2*rg]),   tb);
        tb = dot2(uh(v1p.y), uh(g2p[16+m*8+2*rg+1]), tb);
      }
    }
    ta *= fast_sig(za); tb *= fast_sig(zb);
    h2v tp = mkh2(ta, tb);
    uint4 a = sPI1C[2*p], b = sPI1C[2*p+1];
    ac[0] = dot2(uh(a.x), tp, ac[0]);
    ac[1] = dot2(uh(a.y), tp, ac[1]);
    ac[2] = dot2(uh(a.z), tp, ac[2]);
    ac[3] = dot2(uh(a.w), tp, ac[3]);
    ac[4] = dot2(uh(b.x), tp, ac[4]);
    ac[5] = dot2(uh(b.y), tp, ac[5]);
  }

  // ============ V, dV ============
  float hdiff = y - sYREF;
  float sigma = (hdiff >= 1.0f) ? (hdiff - 0.5f) : ((hdiff > 0.0f) ? 0.5f*hdiff*hdiff : 0.0f);
  float sigp  = (hdiff >= 1.0f) ? 1.0f          : ((hdiff > 0.0f) ? hdiff             : 0.0f);
  float dx2 = 0.0f;
  float dV[6];
  #pragma unroll
  for (int d = 0; d < 6; d++){
    float dx = x[d] - sXREF[d];
    dx2 = fmaf(dx, dx, dx2);
    dV[d] = fmaf(sigp, ac[d], 2.0f*EPS*dx);
  }
  float V = sigma + EPS*dx2;

  float sc = ALPHA * V;
  #pragma unroll
  for (int d = 0; d < 6; d++) sc = fmaf(dV[d], f[d], sc);

  // ============ GNN + combine ============
  float u[6];
  #pragma unroll
  for (int m = 0; m < 6; m++) u[m] = valid ? U[(long)i*6 + m] : 0.0f;
  float am[6] = {0.f,0.f,0.f,0.f,0.f,0.f};
  float gU[6];
  #pragma unroll
  for (int d = 0; d < 6; d++){
    float acc = 0.0f;
    #pragma unroll
    for (int m = 0; m < 6; m++){
      int o = d*6 + m;
      uint4 g4 = sPGB[o];
      float g = uf(g4.w);
      g = dot2(uh(g4.x), xp[0], g); g = dot2(uh(g4.y), xp[1], g); g = dot2(uh(g4.z), xp[2], g);
      am[m] = fmaf(dV[d], g, am[m]);
      acc   = fmaf(g, u[m], acc);
    }
    gU[d] = acc;
  }
  #pragma unroll
  for (int m = 0; m < 6; m++) sc -= fabsf(am[m]);

  float n2 = 0.0f;
  #pragma unroll
  for (int d = 0; d < 6; d++) n2 = fmaf(dV[d], dV[d], n2);
  float r = fmaxf(sc, 0.0f) * rcp_f(n2);

  if (valid){
    #pragma unroll
    for (int d = 0; d < 6; d++)
      out[(long)i*6 + d] = f[d] - dV[d]*r + gU[d];
  }
}

extern "C" void kernel_launch(void* const* d_in, const int* in_sizes, int n_in,
                              void* d_out, int out_size, void* d_ws, size_t ws_size,
                              hipStream_t stream)
{
  const float* X    = (const float*)d_in[0];
  const float* U    = (const float*)d_in[1];
  const float* xref = (const float*)d_in[2];
  const float* fw1  = (const float*)d_in[3];
  const float* fb1  = (const float*)d_in[4];
  const float* fw2  = (const float*)d_in[5];
  const float* fb2  = (const float*)d_in[6];
  const float* fw3  = (const float*)d_in[7];
  const float* fb3  = (const float*)d_in[8];
  const float* gw   = (const float*)d_in[9];
  const float* gb   = (const float*)d_in[10];
  const float* iw1  = (const float*)d_in[11];
  const float* ib1  = (const float*)d_in[12];
  const float* iw2  = (const float*)d_in[13];
  const float* ib2  = (const float*)d_in[14];
  const float* iw3  = (const float*)d_in[15];
  const float* ib3  = (const float*)d_in[16];
  const float* iw4  = (const float*)d_in[17];
  const float* ib4  = (const float*)d_in[18];
  const float* im2  = (const float*)d_in[19];
  const float* im3  = (const float*)d_in[20];
  const float* im4  = (const float*)d_in[21];

  float* out = (float*)d_out;
  int N = in_sizes[0] / 6;

  int threads = 512;
  int blocks  = (N + threads - 1) / threads;
  holo_main<<<blocks, threads, 0, stream>>>(X, U, xref,
      fw1, fb1, fw2, fb2, fw3, fb3, gw, gb,
      iw1, ib1, iw2, ib2, iw3, ib3, iw4, ib4, im2, im3, im4,
      out, N);
}

// Round 9
// 236.702 us; speedup vs baseline: 8.5230x; 8.1272x over previous
//
#include <hip/hip_runtime.h>

#define EPS 1e-05f
#define ALPHA 0.05f

typedef _Float16 h2v __attribute__((ext_vector_type(2)));
typedef _Float16 f16x8 __attribute__((ext_vector_type(8)));
typedef float f32x16 __attribute__((ext_vector_type(16)));

__device__ __forceinline__ float rcp_f(float x){ return __builtin_amdgcn_rcpf(x); }
__device__ __forceinline__ float dot2(h2v a, h2v b, float c){
  return __builtin_amdgcn_fdot2(a, b, c, false);
}
__device__ __forceinline__ h2v uh(uint u){ return __builtin_bit_cast(h2v, u); }
__device__ __forceinline__ float uf(uint u){ return __builtin_bit_cast(float, u); }

#define LOG2E 1.4426950408889634f
#define LN2   0.6931471805599453f

__device__ __forceinline__ float fast_tanh(float x){
  float ax = fabsf(x);
  float e  = exp2f(ax * (-2.0f * LOG2E));
  float t  = (1.0f - e) * rcp_f(1.0f + e);
  return copysignf(t, x);
}
__device__ __forceinline__ float fast_sp(float x){
  float ax = fabsf(x);
  float e  = exp2f(ax * -LOG2E);
  return fmaxf(x, 0.0f) + log2f(1.0f + e) * LN2;
}
__device__ __forceinline__ float fast_sig(float x){
  float ax = fabsf(x);
  float e  = exp2f(ax * -LOG2E);
  float r  = rcp_f(1.0f + e);
  return x >= 0.0f ? r : e * r;
}
__device__ __forceinline__ float sig_from_sp(float sp){
  return 1.0f - exp2f(sp * -LOG2E);
}
__device__ __forceinline__ h2v mkh2(float a, float b){
  h2v r; r.x = (_Float16)a; r.y = (_Float16)b; return r;
}
__device__ __forceinline__ uint packh(float a, float b){
  ushort lo = __builtin_bit_cast(ushort, (_Float16)a);
  ushort hi = __builtin_bit_cast(ushort, (_Float16)b);
  return (uint)lo | ((uint)hi << 16);
}

// ---- packed-weight layout (uint units) ----
static constexpr int O_PW1B = 0;     // [80][4]  fw1 row: w01,w23,w45, fb1
static constexpr int O_PGB  = 320;   // [36][4]  gw  row: w01,w23,w45, gb
static constexpr int O_PI1B = 464;   // [30][8]  iw1 rows 2p,2p+1: {w,w,w,b}x2
static constexpr int O_PI1C = 704;   // [30][8]  iw1^T pairs: c<6
static constexpr int O_PI3  = 944;   // [30][32] iw3 row pairs (q<30)
static constexpr int O_PI3C = 1904;  // [64][16] iw3^T (j<60, q<15)
static constexpr int O_PM2B = 2928;  // [64][4]  im2 row: w,w,w, ib2
static constexpr int O_PM2C = 3184;  // [32][8]  im2^T pairs (q<30, c<6)
static constexpr int O_PM3B = 3440;  // [30][8]  im3 row: w,w,w, ib3, iw4
static constexpr int O_PM3C = 3680;  // [15][8]  im3^T pairs (c<6)
static constexpr int O_PM4  = 3800;  // [4]      im4 pairs
static constexpr int O_FB3  = 3804;  // [6] f32
static constexpr int O_XREF = 3810;  // [6] f32
static constexpr int O_IM4  = 3816;  // [6] f32
static constexpr int O_IB4  = 3822;  // [1] f32
static constexpr int O_YREF = 3823;  // [1] f32
static constexpr int O_PI2T = 3824;  // [30][60] iw2 k1-pair stream
static constexpr int O_PI2C = 5624;  // [60][32] iw2^T (q<30)
static constexpr int W_TOTAL = 7544;

__device__ uint g_stage[W_TOTAL];
__constant__ uint cW[W_TOTAL];

// ================= prep: pack weights + compute yref =================
__global__ void holo_prep(
    const float* __restrict__ xref,
    const float* __restrict__ fw1, const float* __restrict__ fb1,
    const float* __restrict__ fb3,
    const float* __restrict__ gw,  const float* __restrict__ gb,
    const float* __restrict__ iw1, const float* __restrict__ ib1,
    const float* __restrict__ iw2, const float* __restrict__ ib2,
    const float* __restrict__ iw3, const float* __restrict__ ib3,
    const float* __restrict__ iw4, const float* __restrict__ ib4,
    const float* __restrict__ im2, const float* __restrict__ im3,
    const float* __restrict__ im4)
{
  uint* gs = g_stage;
  const int t = threadIdx.x, T = 256;
  __shared__ float sS1[60], sS2[60], sS3[30];

  for (int idx=t; idx<320; idx+=T){
    int o = idx/4, c = idx%4;
    gs[O_PW1B+idx] = (c<3) ? packh(fw1[o*6+2*c], fw1[o*6+2*c+1])
                           : __builtin_bit_cast(uint, fb1[o]);
  }
  for (int idx=t; idx<144; idx+=T){
    int o = idx/4, c = idx%4;
    gs[O_PGB+idx] = (c<3) ? packh(gw[o*6+2*c], gw[o*6+2*c+1])
                          : __builtin_bit_cast(uint, gb[o]);
  }
  for (int idx=t; idx<240; idx+=T){
    int p = idx/8, c = idx%8, sub = c/4, cc = c%4, nr = 2*p+sub;
    gs[O_PI1B+idx] = (cc<3) ? packh(iw1[nr*6+2*cc], iw1[nr*6+2*cc+1])
                            : __builtin_bit_cast(uint, ib1[nr]);
  }
  for (int idx=t; idx<240; idx+=T){
    int q = idx/8, c = idx%8;
    gs[O_PI1C+idx] = (c<6) ? packh(iw1[(2*q)*6+c], iw1[(2*q+1)*6+c]) : 0u;
  }
  for (int idx=t; idx<960; idx+=T){
    int r = idx/32, q = idx%32;
    gs[O_PI3+idx] = (q<30) ? packh(iw3[r*60+2*q], iw3[r*60+2*q+1]) : 0u;
  }
  for (int idx=t; idx<1024; idx+=T){
    int j = idx/16, q = idx%16;
    gs[O_PI3C+idx] = (j<60 && q<15) ? packh(iw3[(2*q)*60+j], iw3[(2*q+1)*60+j]) : 0u;
  }
  for (int idx=t; idx<256; idx+=T){
    int j = idx/4, c = idx%4;
    uint v = 0;
    if (j < 60) v = (c<3) ? packh(im2[j*6+2*c], im2[j*6+2*c+1])
                          : __builtin_bit_cast(uint, ib2[j]);
    gs[O_PM2B+idx] = v;
  }
  for (int idx=t; idx<256; idx+=T){
    int q = idx/8, c = idx%8;
    gs[O_PM2C+idx] = (q<30 && c<6) ? packh(im2[(2*q)*6+c], im2[(2*q+1)*6+c]) : 0u;
  }
  for (int idx=t; idx<240; idx+=T){
    int r = idx/8, c = idx%8;
    uint v = 0;
    if (c < 3)       v = packh(im3[r*6+2*c], im3[r*6+2*c+1]);
    else if (c == 3) v = __builtin_bit_cast(uint, ib3[r]);
    else if (c == 4) v = __builtin_bit_cast(uint, iw4[r]);
    gs[O_PM3B+idx] = v;
  }
  for (int idx=t; idx<120; idx+=T){
    int q = idx/8, c = idx%8;
    gs[O_PM3C+idx] = (c<6) ? packh(im3[(2*q)*6+c], im3[(2*q+1)*6+c]) : 0u;
  }
  for (int idx=t; idx<4; idx+=T)
    gs[O_PM4+idx] = (idx<3) ? packh(im4[2*idx], im4[2*idx+1]) : 0u;
  for (int k=t; k<6; k+=T){
    gs[O_FB3+k]  = __builtin_bit_cast(uint, fb3[k]);
    gs[O_XREF+k] = __builtin_bit_cast(uint, xref[k]);
    gs[O_IM4+k]  = __builtin_bit_cast(uint, im4[k]);
  }
  if (t==0) gs[O_IB4] = __builtin_bit_cast(uint, ib4[0]);
  for (int idx=t; idx<1800; idx+=T){
    int p = idx/60, j = idx%60;
    gs[O_PI2T+idx] = packh(iw2[j*60+2*p], iw2[j*60+2*p+1]);
  }
  for (int idx=t; idx<1920; idx+=T){
    int k1 = idx/32, q = idx%32;
    gs[O_PI2C+idx] = (q<30) ? packh(iw2[(2*q)*60+k1], iw2[(2*q+1)*60+k1]) : 0u;
  }
  __threadfence_block();
  __syncthreads();

  // ---- yref = icnn(xref) with the SAME f16-rounded weights ----
  h2v xrp[3];
  #pragma unroll
  for (int p = 0; p < 3; p++) xrp[p] = mkh2(xref[2*p], xref[2*p+1]);
  if (t < 60){
    const uint* w = gs + O_PI1B + (t/2)*8 + (t&1)*4;
    float z = uf(w[3]);
    #pragma unroll
    for (int c = 0; c < 3; c++) z = dot2(uh(w[c]), xrp[c], z);
    sS1[t] = fast_sp(z);
  }
  __syncthreads();
  if (t < 60){
    const uint* m = gs + O_PM2B + t*4;
    float z = uf(m[3]);
    #pragma unroll
    for (int c = 0; c < 3; c++) z = dot2(uh(m[c]), xrp[c], z);
    for (int p = 0; p < 30; p++)
      z = dot2(uh(gs[O_PI2T + p*60 + t]), mkh2(sS1[2*p], sS1[2*p+1]), z);
    sS2[t] = fast_sp(z);
  }
  __syncthreads();
  if (t < 30){
    const uint* m = gs + O_PM3B + t*8;
    float z = uf(m[3]);
    #pragma unroll
    for (int c = 0; c < 3; c++) z = dot2(uh(m[c]), xrp[c], z);
    for (int q = 0; q < 30; q++)
      z = dot2(uh(gs[O_PI3 + t*32 + q]), mkh2(sS2[2*q], sS2[2*q+1]), z);
    sS3[t] = fast_sp(z);
  }
  __syncthreads();
  if (t == 0){
    float y = uf(gs[O_IB4]);
    #pragma unroll
    for (int p = 0; p < 3; p++) y = dot2(uh(gs[O_PM4+p]), xrp[p], y);
    for (int j = 0; j < 30; j++) y = fmaf(uf(gs[O_PM3B+j*8+4]), sS3[j], y);
    gs[O_YREF] = __builtin_bit_cast(uint, y);
  }
}

// ================= main: SMEM weights + FNN MFMA =================
__global__ __launch_bounds__(512, 2) void holo_main(
    const float* __restrict__ X, const float* __restrict__ U,
    const float* __restrict__ fw2, const float* __restrict__ fb2,
    const float* __restrict__ fw3,
    float* __restrict__ out, int N)
{
  // LDS: only the lane-divergent tables
  __shared__ alignas(16) ushort sW2r[224*84]; // fw2 MFMA-A [224 rows][84 halves]
  __shared__ uint4 sW3E[224];   // 112 n-pairs x2: {w3 d0..d5 pairs, fb2[n], fb2[n+1]}

  const int t = threadIdx.x;
  const int T = 512;
  const int lane = t & 63;
  const int hh  = lane >> 5;
  const int l31 = lane & 31;

  for (int idx=t; idx<224*42; idx+=T){
    int row = idx/42, c = idx%42, k = 2*c;
    uint v = 0;
    if (row < 200 && k < 80) v = packh(fw2[row*80+k], fw2[row*80+k+1]);
    ((uint*)sW2r)[idx] = v;
  }
  for (int idx=t; idx<896; idx+=T){
    int P = idx/8, c = idx%8, n = 2*P;
    uint v = 0;
    if (n < 200){
      if (c < 6)       v = packh(fw3[c*200+n], fw3[c*200+n+1]);
      else if (c == 6) v = __builtin_bit_cast(uint, fb2[n]);
      else             v = __builtin_bit_cast(uint, fb2[n+1]);
    }
    ((uint*)sW3E)[idx] = v;
  }
  __syncthreads();

  const int i = blockIdx.x * blockDim.x + t;
  const bool valid = (i < N);

  float x[6]; h2v xp[3];
  #pragma unroll
  for (int k = 0; k < 6; k++) x[k] = valid ? X[(long)i*6 + k] : 0.0f;
  #pragma unroll
  for (int p = 0; p < 3; p++) xp[p] = mkh2(x[2*p], x[2*p+1]);

  // ============ FNN layer 1: 6 -> 80, tanh (SGPR weights) ============
  uint h1u[40];
  #pragma unroll
  for (int o = 0; o < 80; o += 2){
    float z0 = uf(cW[O_PW1B + o*4 + 3]), z1 = uf(cW[O_PW1B + (o+1)*4 + 3]);
    #pragma unroll
    for (int c = 0; c < 3; c++){
      z0 = dot2(uh(cW[O_PW1B + o*4 + c]),     xp[c], z0);
      z1 = dot2(uh(cW[O_PW1B + (o+1)*4 + c]), xp[c], z1);
    }
    h1u[o/2] = packh(fast_tanh(z0), fast_tanh(z1));
  }

  // ============ FNN L2+L3 via MFMA (32x32x16 f16) ============
  uint bf0[5][4], bf1[5][4];
  {
    int a0 = 4 * l31;
    int a1 = 4 * (32 + l31);
    #pragma unroll
    for (int kt = 0; kt < 5; kt++){
      #pragma unroll
      for (int q = 0; q < 4; q++){
        int lo0 = __builtin_amdgcn_ds_bpermute(a0, (int)h1u[kt*8 + q]);
        int hi0 = __builtin_amdgcn_ds_bpermute(a0, (int)h1u[kt*8 + 4 + q]);
        bf0[kt][q] = hh ? (uint)hi0 : (uint)lo0;
        int lo1 = __builtin_amdgcn_ds_bpermute(a1, (int)h1u[kt*8 + q]);
        int hi1 = __builtin_amdgcn_ds_bpermute(a1, (int)h1u[kt*8 + 4 + q]);
        bf1[kt][q] = hh ? (uint)hi1 : (uint)lo1;
      }
    }
  }

  float fp0[6] = {0.f,0.f,0.f,0.f,0.f,0.f};
  float fp1[6] = {0.f,0.f,0.f,0.f,0.f,0.f};
  for (int mt = 0; mt < 7; mt++){
    const int row = mt*32 + l31;
    f16x8 af[5];
    #pragma unroll
    for (int kt = 0; kt < 5; kt++){
      const ushort* wp = &sW2r[row*84 + kt*16 + 8*hh];
      uint2 w0 = *(const uint2*)wp;
      uint2 w1 = *(const uint2*)(wp + 4);
      uint4 au; au.x = w0.x; au.y = w0.y; au.z = w1.x; au.w = w1.y;
      af[kt] = __builtin_bit_cast(f16x8, au);
    }
    f32x16 acc0 = {0,0,0,0,0,0,0,0,0,0,0,0,0,0,0,0};
    f32x16 acc1 = {0,0,0,0,0,0,0,0,0,0,0,0,0,0,0,0};
    #pragma unroll
    for (int kt = 0; kt < 5; kt++){
      uint4 b0u; b0u.x=bf0[kt][0]; b0u.y=bf0[kt][1]; b0u.z=bf0[kt][2]; b0u.w=bf0[kt][3];
      uint4 b1u; b1u.x=bf1[kt][0]; b1u.y=bf1[kt][1]; b1u.z=bf1[kt][2]; b1u.w=bf1[kt][3];
      acc0 = __builtin_amdgcn_mfma_f32_32x32x16_f16(af[kt], __builtin_bit_cast(f16x8, b0u), acc0, 0, 0, 0);
      acc1 = __builtin_amdgcn_mfma_f32_32x32x16_f16(af[kt], __builtin_bit_cast(f16x8, b1u), acc1, 0, 0, 0);
    }
    // epilogue (neuron pairs); rows 200-223 are zero-pad -> mt==6 keeps only c==0
    #pragma unroll
    for (int c = 0; c < 4; c++){
      #pragma unroll
      for (int b0h = 0; b0h < 2; b0h++){
        if (mt == 6 && c > 0) continue;
        const int r0 = 4*c + 2*b0h;
        const int P  = mt*16 + 4*c + 2*hh + b0h;
        uint4 wa = sW3E[P*2], wb = sW3E[P*2+1];
        float bA = uf(wb.z), bB = uf(wb.w);
        h2v tp0 = mkh2(fast_tanh(acc0[r0] + bA), fast_tanh(acc0[r0+1] + bB));
        h2v tp1 = mkh2(fast_tanh(acc1[r0] + bA), fast_tanh(acc1[r0+1] + bB));
        fp0[0] = dot2(uh(wa.x), tp0, fp0[0]); fp1[0] = dot2(uh(wa.x), tp1, fp1[0]);
        fp0[1] = dot2(uh(wa.y), tp0, fp0[1]); fp1[1] = dot2(uh(wa.y), tp1, fp1[1]);
        fp0[2] = dot2(uh(wa.z), tp0, fp0[2]); fp1[2] = dot2(uh(wa.z), tp1, fp1[2]);
        fp0[3] = dot2(uh(wa.w), tp0, fp0[3]); fp1[3] = dot2(uh(wa.w), tp1, fp1[3]);
        fp0[4] = dot2(uh(wb.x), tp0, fp0[4]); fp1[4] = dot2(uh(wb.x), tp1, fp1[4]);
        fp0[5] = dot2(uh(wb.y), tp0, fp0[5]); fp1[5] = dot2(uh(wb.y), tp1, fp1[5]);
      }
    }
  }
  float f[6];
  #pragma unroll
  for (int d = 0; d < 6; d++){
    float s0 = fp0[d] + __shfl_xor(fp0[d], 32, 64);
    float s1 = fp1[d] + __shfl_xor(fp1[d], 32, 64);
    f[d] = uf(cW[O_FB3+d]) + (hh ? s1 : s0);
  }

  // ============ ICNN forward (SGPR weights) ============
  float c2[60];
  #pragma unroll
  for (int j = 0; j < 60; j++){
    float z = uf(cW[O_PM2B + j*4 + 3]);
    z = dot2(uh(cW[O_PM2B+j*4+0]), xp[0], z);
    z = dot2(uh(cW[O_PM2B+j*4+1]), xp[1], z);
    z = dot2(uh(cW[O_PM2B+j*4+2]), xp[2], z);
    c2[j] = z;
  }
  for (int p = 0; p < 30; p++){           // k1 pairs, streamed (rolled)
    float za = uf(cW[O_PI1B + p*8 + 3]);
    float zb = uf(cW[O_PI1B + p*8 + 7]);
    #pragma unroll
    for (int c = 0; c < 3; c++){
      za = dot2(uh(cW[O_PI1B + p*8 + c]),     xp[c], za);
      zb = dot2(uh(cW[O_PI1B + p*8 + 4 + c]), xp[c], zb);
    }
    h2v s = mkh2(fast_sp(za), fast_sp(zb));
    #pragma unroll
    for (int j = 0; j < 60; j++)
      c2[j] = dot2(uh(cW[O_PI2T + p*60 + j]), s, c2[j]);
  }
  h2v c2p[30];
  #pragma unroll
  for (int j = 0; j < 60; j += 2)
    c2p[j/2] = mkh2(fast_sp(c2[j]), fast_sp(c2[j+1]));

  // z3 fwd + y + g3
  float y = uf(cW[O_IB4]);
  #pragma unroll
  for (int p = 0; p < 3; p++) y = dot2(uh(cW[O_PM4+p]), xp[p], y);
  float ac[6];
  #pragma unroll
  for (int d = 0; d < 6; d++) ac[d] = uf(cW[O_IM4+d]);
  h2v g3p[15];
  float g3even;
  #pragma unroll
  for (int i3 = 0; i3 < 30; i3++){
    float z = uf(cW[O_PM3B + i3*8 + 3]);
    z = dot2(uh(cW[O_PM3B+i3*8+0]), xp[0], z);
    z = dot2(uh(cW[O_PM3B+i3*8+1]), xp[1], z);
    z = dot2(uh(cW[O_PM3B+i3*8+2]), xp[2], z);
    #pragma unroll
    for (int q = 0; q < 30; q++)
      z = dot2(uh(cW[O_PI3 + i3*32 + q]), c2p[q], z);
    float sp3 = fast_sp(z);
    float w4  = uf(cW[O_PM3B + i3*8 + 4]);
    y = fmaf(w4, sp3, y);
    float gi = w4 * sig_from_sp(sp3);
    if (i3 & 1) g3p[i3>>1] = mkh2(g3even, gi); else g3even = gi;
  }
  #pragma unroll
  for (int q = 0; q < 15; q++){
    #pragma unroll
    for (int d = 0; d < 6; d++)
      ac[d] = dot2(uh(cW[O_PM3C + q*8 + d]), g3p[q], ac[d]);
  }

  // bwd g2
  h2v g2p[30];
  #pragma unroll
  for (int jp = 0; jp < 30; jp++){
    float ta = 0.0f, tb = 0.0f;
    #pragma unroll
    for (int q = 0; q < 15; q++){
      ta = dot2(uh(cW[O_PI3C + (2*jp)*16 + q]),   g3p[q], ta);
      tb = dot2(uh(cW[O_PI3C + (2*jp+1)*16 + q]), g3p[q], tb);
    }
    h2v sp = c2p[jp];
    ta *= sig_from_sp((float)sp.x);
    tb *= sig_from_sp((float)sp.y);
    h2v tp = mkh2(ta, tb);
    g2p[jp] = tp;
    #pragma unroll
    for (int d = 0; d < 6; d++)
      ac[d] = dot2(uh(cW[O_PM2C + jp*8 + d]), tp, ac[d]);
  }

  // bwd g1 (z1 recomputed; rolled outer)
  for (int p = 0; p < 30; p++){
    float za = uf(cW[O_PI1B + p*8 + 3]);
    float zb = uf(cW[O_PI1B + p*8 + 7]);
    #pragma unroll
    for (int c = 0; c < 3; c++){
      za = dot2(uh(cW[O_PI1B + p*8 + c]),     xp[c], za);
      zb = dot2(uh(cW[O_PI1B + p*8 + 4 + c]), xp[c], zb);
    }
    float ta = 0.0f, tb = 0.0f;
    #pragma unroll
    for (int q = 0; q < 30; q++){
      ta = dot2(uh(cW[O_PI2C + (2*p)*32 + q]),   g2p[q], ta);
      tb = dot2(uh(cW[O_PI2C + (2*p+1)*32 + q]), g2p[q], tb);
    }
    ta *= fast_sig(za); tb *= fast_sig(zb);
    h2v tp = mkh2(ta, tb);
    #pragma unroll
    for (int d = 0; d < 6; d++)
      ac[d] = dot2(uh(cW[O_PI1C + p*8 + d]), tp, ac[d]);
  }

  // ============ V, dV ============
  float hdiff = y - uf(cW[O_YREF]);
  float sigma = (hdiff >= 1.0f) ? (hdiff - 0.5f) : ((hdiff > 0.0f) ? 0.5f*hdiff*hdiff : 0.0f);
  float sigp  = (hdiff >= 1.0f) ? 1.0f          : ((hdiff > 0.0f) ? hdiff             : 0.0f);
  float dx2 = 0.0f;
  float dV[6];
  #pragma unroll
  for (int d = 0; d < 6; d++){
    float dx = x[d] - uf(cW[O_XREF+d]);
    dx2 = fmaf(dx, dx, dx2);
    dV[d] = fmaf(sigp, ac[d], 2.0f*EPS*dx);
  }
  float V = sigma + EPS*dx2;

  float sc = ALPHA * V;
  #pragma unroll
  for (int d = 0; d < 6; d++) sc = fmaf(dV[d], f[d], sc);

  // ============ GNN + combine ============
  float u[6];
  #pragma unroll
  for (int m = 0; m < 6; m++) u[m] = valid ? U[(long)i*6 + m] : 0.0f;
  float am[6] = {0.f,0.f,0.f,0.f,0.f,0.f};
  float gU[6];
  #pragma unroll
  for (int d = 0; d < 6; d++){
    float acc = 0.0f;
    #pragma unroll
    for (int m = 0; m < 6; m++){
      int o = d*6 + m;
      float g = uf(cW[O_PGB + o*4 + 3]);
      g = dot2(uh(cW[O_PGB+o*4+0]), xp[0], g);
      g = dot2(uh(cW[O_PGB+o*4+1]), xp[1], g);
      g = dot2(uh(cW[O_PGB+o*4+2]), xp[2], g);
      am[m] = fmaf(dV[d], g, am[m]);
      acc   = fmaf(g, u[m], acc);
    }
    gU[d] = acc;
  }
  #pragma unroll
  for (int m = 0; m < 6; m++) sc -= fabsf(am[m]);

  float n2 = 0.0f;
  #pragma unroll
  for (int d = 0; d < 6; d++) n2 = fmaf(dV[d], dV[d], n2);
  float r = fmaxf(sc, 0.0f) * rcp_f(n2);

  if (valid){
    #pragma unroll
    for (int d = 0; d < 6; d++)
      out[(long)i*6 + d] = f[d] - dV[d]*r + gU[d];
  }
}

extern "C" void kernel_launch(void* const* d_in, const int* in_sizes, int n_in,
                              void* d_out, int out_size, void* d_ws, size_t ws_size,
                              hipStream_t stream)
{
  const float* X    = (const float*)d_in[0];
  const float* U    = (const float*)d_in[1];
  const float* xref = (const float*)d_in[2];
  const float* fw1  = (const float*)d_in[3];
  const float* fb1  = (const float*)d_in[4];
  const float* fw2  = (const float*)d_in[5];
  const float* fb2  = (const float*)d_in[6];
  const float* fw3  = (const float*)d_in[7];
  const float* fb3  = (const float*)d_in[8];
  const float* gw   = (const float*)d_in[9];
  const float* gb   = (const float*)d_in[10];
  const float* iw1  = (const float*)d_in[11];
  const float* ib1  = (const float*)d_in[12];
  const float* iw2  = (const float*)d_in[13];
  const float* ib2  = (const float*)d_in[14];
  const float* iw3  = (const float*)d_in[15];
  const float* ib3  = (const float*)d_in[16];
  const float* iw4  = (const float*)d_in[17];
  const float* ib4  = (const float*)d_in[18];
  const float* im2  = (const float*)d_in[19];
  const float* im3  = (const float*)d_in[20];
  const float* im4  = (const float*)d_in[21];

  float* out = (float*)d_out;
  int N = in_sizes[0] / 6;

  holo_prep<<<1, 256, 0, stream>>>(xref, fw1, fb1, fb3, gw, gb,
                                   iw1, ib1, iw2, ib2, iw3, ib3,
                                   iw4, ib4, im2, im3, im4);

  void* stage_ptr = nullptr;
  void* const_ptr = nullptr;
  hipGetSymbolAddress(&stage_ptr, HIP_SYMBOL(g_stage));
  hipGetSymbolAddress(&const_ptr, HIP_SYMBOL(cW));
  hipMemcpyAsync(const_ptr, stage_ptr, W_TOTAL * sizeof(uint),
                 hipMemcpyDeviceToDevice, stream);

  int threads = 512;
  int blocks  = (N + threads - 1) / threads;
  holo_main<<<blocks, threads, 0, stream>>>(X, U, fw2, fb2, fw3, out, N);
}